// Round 9
// baseline (57.484 us; speedup 1.0000x reference)
//
#include <hip/hip_runtime.h>
#include <math.h>

typedef unsigned short u16;
typedef unsigned int u32;
typedef __bf16 bf16x8 __attribute__((ext_vector_type(8)));
typedef float f32x4 __attribute__((ext_vector_type(4)));

// Problem constants
#define BB   4      // B
#define DD   256    // d
#define NN   256    // n
#define CH   128    // CHUNK
#define NCH  16     // T/CHUNK
#define EPSF 1e-8f

// Workspace byte offsets
#define WS_QB  0u           // qb   bf16 [T][B][N]          4 MB
#define WS_VT  (4u<<20)     // vT   bf16 [CB][D][S=128]     4 MB
#define WS_WT  (8u<<20)     // wT   bf16 [CB][N][S=128]     4 MB
#define WS_WN  (12u<<20)    // w_n  bf16 [CB][S][N]         4 MB
#define WS_AST (16u<<20)    // AsT  bf16 [CB][T=128][S=128] 2 MB
#define WS_SPT (18u<<20)    // sptT bf16 [CB][D][N]         8 MB
#define WS_PF  (26u<<20)    // pf   f32  [CB][N]            64 KB

__device__ __forceinline__ u16 f2bf(float x) {
  u32 u = __float_as_uint(x);
  u32 r = (u + 0x7fffu + ((u >> 16) & 1u)) >> 16;
  return (u16)r;
}

__device__ __forceinline__ void gload16(void* lds, const void* g) {
  __builtin_amdgcn_global_load_lds((const __attribute__((address_space(1))) void*)g,
                                   (__attribute__((address_space(3))) void*)lds, 16, 0, 0);
}

// Stage a 64x64 bf16 tile (row-major, rowstride in elems) into linear LDS.
// Slot-XOR swizzle applied on the GLOBAL source address (m173 pattern).
__device__ __forceinline__ void stage_tile(u16* lds, const u16* g, int rowstride) {
  int tid = threadIdx.x;
#pragma unroll
  for (int h = 0; h < 2; h++) {
    int ci = tid + h * 256;
    int r = ci >> 3, sl = ci & 7;
    const u16* src = g + (size_t)r * rowstride + ((sl ^ (r & 7)) << 3);
    gload16(lds + (size_t)ci * 8, src);
  }
}

// Read 2x2 fragments with matching swizzle. Chunk index ks*4+(lane>>4) (R7 fix).
__device__ __forceinline__ void read_frags(const u16* buf, int rbase, int lane,
                                           bf16x8 (&f)[2][2]) {
#pragma unroll
  for (int i = 0; i < 2; i++)
#pragma unroll
    for (int ks = 0; ks < 2; ks++) {
      int r = rbase + i * 16 + (lane & 15);
      int slot = ((ks << 2) + (lane >> 4)) ^ (r & 7);
      f[i][ks] = *reinterpret_cast<const bf16x8*>(buf + r * 64 + slot * 8);
    }
}

__device__ __forceinline__ void mma_step(const u16* Ab, const u16* Bb, int rm, int cn,
                                         int lane, f32x4 (&acc)[2][2]) {
  bf16x8 a[2][2], b[2][2];
  read_frags(Ab, rm, lane, a);
  read_frags(Bb, cn, lane, b);
#pragma unroll
  for (int mf = 0; mf < 2; mf++)
#pragma unroll
    for (int nf = 0; nf < 2; nf++)
#pragma unroll
      for (int ks = 0; ks < 2; ks++)
        acc[mf][nf] = __builtin_amdgcn_mfma_f32_16x16x32_bf16(a[mf][ks], b[nf][ks],
                                                              acc[mf][nf], 0, 0, 0);
}

// ---------------------------------------------------------------------------
// k_prep: merged wpf (bid<1024) | trv (bid<1280) | convq (bid<2304).
__global__ __launch_bounds__(256) void k_prep(const float* __restrict__ q,
                                              const float* __restrict__ v,
                                              const float* __restrict__ kin,
                                              const float* __restrict__ alpha,
                                              u16* __restrict__ qb,
                                              u16* __restrict__ vT,
                                              u16* __restrict__ wT,
                                              u16* __restrict__ wn,
                                              float* __restrict__ pf) {
  __shared__ __align__(16) char smem[64 * 136 * 2];  // max of branch needs
  int bid = blockIdx.x;
  int tid = threadIdx.x;
  if (bid < 1024) {
    // ---- wpf: segmented scan ----
    int ng = bid & 15, b = (bid >> 4) & 3, c = bid >> 6;
    int nn = tid & 15, seg = tid >> 4;
    int n = ng * 16 + nn;
    int cb = c * BB + b;
    const int stride = BB * NN;
    size_t gbase = ((size_t)(c * CH + seg * 8) * stride) + b * NN + n;
    float lg[8], kv[8];
    float a0 = 0.f, run = 0.f;
#pragma unroll
    for (int i = 0; i < 8; i++) {
      float av = fmaxf(alpha[gbase + (size_t)i * stride], EPSF);
      kv[i] = kin[gbase + (size_t)i * stride];
      if (i == 0) a0 = av;
      run += __logf(av);
      lg[i] = run;
    }
    float (*tot)[17] = (float(*)[17])smem;
    tot[seg][nn] = run;
    __syncthreads();
    float prefix = 0.f, total = 0.f;
#pragma unroll
    for (int j = 0; j < 16; j++) {
      float tv = tot[j][nn];
      if (j < seg) prefix += tv;
      total += tv;
    }
    float rden = 1.f / (__expf(total) + EPSF);
    union { u16 u[8]; uint4 v4; } pk;
    u16* wnrow = wn + (size_t)cb * (CH * NN) + n;
#pragma unroll
    for (int i = 0; i < 8; i++) {
      float cp = __expf(prefix + lg[i]);
      u16 h = f2bf(kv[i] * (cp * rden));
      pk.u[i] = h;
      wnrow[(size_t)(seg * 8 + i) * NN] = h;
    }
    *(uint4*)(wT + (size_t)cb * (NN * CH) + (size_t)n * CH + seg * 8) = pk.v4;
    if (seg == 0) pf[cb * NN + n] = a0;
  } else if (bid < 1280) {
    // ---- trv: v -> vT transpose ----
    int b2 = bid - 1024;
    int dt = b2 & 3, cb = b2 >> 2;
    int c = cb >> 2, b = cb & 3;
    int d0 = dt * 64;
    u16* vt = (u16*)smem;  // [64][136]
    int sr = tid >> 4, chd = tid & 15;
#pragma unroll
    for (int p = 0; p < 8; p++) {
      int s = p * 16 + sr;
      float4 x = *(const float4*)&v[((size_t)(c * CH + s) * BB + b) * DD + d0 + chd * 4];
      int dbase = chd * 4;
      vt[(dbase + 0) * 136 + s] = f2bf(x.x);
      vt[(dbase + 1) * 136 + s] = f2bf(x.y);
      vt[(dbase + 2) * 136 + s] = f2bf(x.z);
      vt[(dbase + 3) * 136 + s] = f2bf(x.w);
    }
    __syncthreads();
    int dr = tid >> 2, ch = tid & 3;
    const uint4* srcl = (const uint4*)&vt[dr * 136 + ch * 32];
    uint4 a0 = srcl[0], a1 = srcl[1], a2 = srcl[2], a3 = srcl[3];
    uint4* dst = (uint4*)&vT[((size_t)cb * DD + d0 + dr) * CH + ch * 32];
    dst[0] = a0; dst[1] = a1; dst[2] = a2; dst[3] = a3;
  } else {
    // ---- convq: q fp32 -> qb bf16 ----
    size_t gid = (size_t)(bid - 1280) * 256 + tid;
    const float4* src = (const float4*)q + gid * 2;
    float4 x = src[0], z = src[1];
    union { u16 u[8]; uint4 v4; } pk;
    pk.u[0] = f2bf(x.x); pk.u[1] = f2bf(x.y); pk.u[2] = f2bf(x.z); pk.u[3] = f2bf(x.w);
    pk.u[4] = f2bf(z.x); pk.u[5] = f2bf(z.y); pk.u[6] = f2bf(z.z); pk.u[7] = f2bf(z.w);
    ((uint4*)qb)[gid] = pk.v4;
  }
}

// ---------------------------------------------------------------------------
// k_mid: bid<64 -> fused UT+scan (S in registers, writes sptT only);
//        bid in [64,256) -> As GEMM + causal mask.
__global__ __launch_bounds__(256) void k_mid(const u16* __restrict__ vT,
                                             const u16* __restrict__ wT,
                                             const float* __restrict__ pf,
                                             const u16* __restrict__ qb,
                                             const u16* __restrict__ wn,
                                             u16* __restrict__ sptT,
                                             u16* __restrict__ asT) {
  __shared__ u16 Al[2][4096], Bl[2][4096];
  int bid = blockIdx.x;
  int tid = threadIdx.x, lane = tid & 63, wv = tid >> 6;
  int rm = (wv >> 1) * 32, cn = (wv & 1) * 32;
  if (bid < 64) {
    int b = bid & 3, dt = (bid >> 2) & 3, nt = bid >> 4;
    f32x4 S[2][2] = {};
    for (int c = 0; c < NCH; c++) {
      int cb = c * BB + b;
      const u16* A = vT + ((size_t)cb * DD + dt * 64) * CH;
      const u16* B = wT + ((size_t)cb * NN + nt * 64) * CH;
      f32x4 acc[2][2] = {};
      stage_tile(Al[0], A, CH); stage_tile(Bl[0], B, CH);
      __syncthreads();
      stage_tile(Al[1], A + 64, CH); stage_tile(Bl[1], B + 64, CH);
      mma_step(Al[0], Bl[0], rm, cn, lane, acc);
      __syncthreads();
      mma_step(Al[1], Bl[1], rm, cn, lane, acc);
      // S update + sptT write (this chunk's incoming state)
      u16* outb = sptT + ((size_t)cb * DD + dt * 64) * NN + nt * 64;
#pragma unroll
      for (int nf = 0; nf < 2; nf++) {
        float p = pf[cb * NN + nt * 64 + cn + nf * 16 + (lane & 15)];
#pragma unroll
        for (int mf = 0; mf < 2; mf++) {
          int row = rm + mf * 16 + (lane >> 4) * 4;
          int col = cn + nf * 16 + (lane & 15);
#pragma unroll
          for (int r = 0; r < 4; r++) {
            float Sp = S[mf][nf][r] * p;
            outb[(size_t)(row + r) * NN + col] = f2bf(Sp);
            S[mf][nf][r] = Sp + acc[mf][nf][r];
          }
        }
      }
    }
  } else {
    int bid2 = bid - 64;
    int tile = bid2 % 3;
    int cb = bid2 / 3;
    int ti = (tile == 0) ? 0 : 1;
    int si = (tile == 2) ? 1 : 0;
    int t0 = ti * 64, s0 = si * 64;
    int c = cb >> 2, b = cb & 3;
    const u16* A = qb + ((size_t)(c * CH + t0) * BB + b) * NN;    // stride 1024
    const u16* B = wn + (size_t)cb * (CH * NN) + (size_t)s0 * NN; // stride 256
    f32x4 acc[2][2] = {};
    stage_tile(Al[0], A, BB * NN); stage_tile(Bl[0], B, NN);
    __syncthreads();
    for (int st = 0; st < 4; st++) {
      int nx = st + 1;
      if (nx < 4) {
        stage_tile(Al[nx & 1], A + nx * 64, BB * NN);
        stage_tile(Bl[nx & 1], B + nx * 64, NN);
      }
      mma_step(Al[st & 1], Bl[st & 1], rm, cn, lane, acc);
      __syncthreads();
    }
    u16* outb = asT + (size_t)cb * (CH * CH);
#pragma unroll
    for (int mf = 0; mf < 2; mf++)
#pragma unroll
      for (int nf = 0; nf < 2; nf++)
#pragma unroll
        for (int r = 0; r < 4; r++) {
          int t = t0 + rm + mf * 16 + (lane >> 4) * 4 + r;
          int s = s0 + cn + nf * 16 + (lane & 15);
          float val = (s <= t) ? acc[mf][nf][r] : 0.f;
          outb[(size_t)t * CH + s] = f2bf(val);
        }
  }
}

// ---------------------------------------------------------------------------
// k_out (MFMA): y[t,d] = sum_n qb[t,n]*sptT[d,n] + sum_s AsT[t,s]*vT[d,s].
__global__ __launch_bounds__(256) void k_out(const u16* __restrict__ qb,
                                             const u16* __restrict__ sptT,
                                             const u16* __restrict__ asT,
                                             const u16* __restrict__ vT,
                                             float* __restrict__ y) {
  int bid = blockIdx.x;
  int dt = bid & 3, tt = (bid >> 2) & 1, cb = bid >> 3;
  int c = cb >> 2, b = cb & 3;
  int t0 = tt * 64, d0 = dt * 64;
  int tid = threadIdx.x, lane = tid & 63, wv = tid >> 6;
  int rm = (wv >> 1) * 32, cn = (wv & 1) * 32;
  const u16* A1 = qb + ((size_t)(c * CH + t0) * BB + b) * NN;      // stride 1024
  const u16* B1 = sptT + ((size_t)cb * DD + d0) * NN;              // stride 256
  const u16* A2 = asT + (size_t)cb * (CH * CH) + (size_t)t0 * CH;  // stride 128
  const u16* B2 = vT + ((size_t)cb * DD + d0) * CH;                // stride 128
  __shared__ u16 Al[2][4096], Bl[2][4096];
  f32x4 acc[2][2] = {};
  int nst = 5 + tt;  // tt=0: s in [0,64) only (rest masked zero, never read)
  stage_tile(Al[0], A1, BB * NN); stage_tile(Bl[0], B1, NN);
  __syncthreads();
  for (int st = 0; st < nst; st++) {
    int nx = st + 1;
    if (nx < 4) {
      stage_tile(Al[nx & 1], A1 + nx * 64, BB * NN);
      stage_tile(Bl[nx & 1], B1 + nx * 64, NN);
    } else if (nx < nst) {
      stage_tile(Al[nx & 1], A2 + (nx - 4) * 64, CH);
      stage_tile(Bl[nx & 1], B2 + (nx - 4) * 64, CH);
    }
    mma_step(Al[st & 1], Bl[st & 1], rm, cn, lane, acc);
    __syncthreads();
  }
  float* out = y + ((size_t)(c * CH + t0) * BB + b) * DD + d0;
#pragma unroll
  for (int mf = 0; mf < 2; mf++)
#pragma unroll
    for (int nf = 0; nf < 2; nf++)
#pragma unroll
      for (int r = 0; r < 4; r++) {
        int row = rm + mf * 16 + (lane >> 4) * 4 + r;
        int col = cn + nf * 16 + (lane & 15);
        out[(size_t)row * (BB * DD) + col] = acc[mf][nf][r];
      }
}

// ---------------------------------------------------------------------------
extern "C" void kernel_launch(void* const* d_in, const int* in_sizes, int n_in,
                              void* d_out, int out_size, void* d_ws, size_t ws_size,
                              hipStream_t stream) {
  const float* v = (const float*)d_in[0];
  const float* k = (const float*)d_in[1];
  const float* alpha = (const float*)d_in[2];
  const float* q = (const float*)d_in[3];
  float* y = (float*)d_out;
  char* ws = (char*)d_ws;
  u16* qb = (u16*)(ws + WS_QB);
  u16* vT = (u16*)(ws + WS_VT);
  u16* wT = (u16*)(ws + WS_WT);
  u16* wn = (u16*)(ws + WS_WN);
  u16* asT = (u16*)(ws + WS_AST);
  u16* sptT = (u16*)(ws + WS_SPT);
  float* pf = (float*)(ws + WS_PF);

  k_prep<<<2304, 256, 0, stream>>>(q, v, k, alpha, qb, vT, wT, wn, pf);
  k_mid<<<256, 256, 0, stream>>>(vT, wT, pf, qb, wn, sptT, asT);
  k_out<<<512, 256, 0, stream>>>(qb, sptT, asT, vT, y);
}

// Round 10
// 40.994 us; speedup vs baseline: 1.4023x; 1.4023x over previous
//
#include <hip/hip_runtime.h>
#include <math.h>

typedef unsigned short u16;
typedef unsigned int u32;
typedef __bf16 bf16x8 __attribute__((ext_vector_type(8)));
typedef float f32x4 __attribute__((ext_vector_type(4)));

// Problem constants
#define BB   4      // B
#define DD   256    // d
#define NN   256    // n
#define CH   128    // CHUNK
#define NCH  16     // T/CHUNK
#define EPSF 1e-8f

// Workspace byte offsets
#define WS_QB  0u           // qb   bf16 [T][B][N]          4 MB
#define WS_VT  (4u<<20)     // vT   bf16 [CB][D][S=128]     4 MB
#define WS_WT  (8u<<20)     // wT   bf16 [CB][N][S=128]     4 MB
#define WS_WN  (12u<<20)    // w_n  bf16 [CB][S][N]         4 MB
#define WS_AST (16u<<20)    // AsT  bf16 [CB][T=128][S=128] 2 MB
#define WS_SPT (18u<<20)    // sptT bf16 [CB][D][N]         8 MB
#define WS_PF  (26u<<20)    // pf   f32  [CB][N]            64 KB
#define WS_UT  (28u<<20)    // utT  bf16 [CB][D][N]         8 MB

__device__ __forceinline__ u16 f2bf(float x) {
  u32 u = __float_as_uint(x);
  u32 r = (u + 0x7fffu + ((u >> 16) & 1u)) >> 16;
  return (u16)r;
}
__device__ __forceinline__ float bf2f(u32 lo16) {
  return __uint_as_float(lo16 << 16);
}

__device__ __forceinline__ void gload16(void* lds, const void* g) {
  __builtin_amdgcn_global_load_lds((const __attribute__((address_space(1))) void*)g,
                                   (__attribute__((address_space(3))) void*)lds, 16, 0, 0);
}

// Stage a 64x64 bf16 tile (row-major, rowstride in elems) into linear LDS.
// Slot-XOR swizzle applied on the GLOBAL source address (m173 pattern).
__device__ __forceinline__ void stage_tile(u16* lds, const u16* g, int rowstride) {
  int tid = threadIdx.x;
#pragma unroll
  for (int h = 0; h < 2; h++) {
    int ci = tid + h * 256;
    int r = ci >> 3, sl = ci & 7;
    const u16* src = g + (size_t)r * rowstride + ((sl ^ (r & 7)) << 3);
    gload16(lds + (size_t)ci * 8, src);
  }
}

// Read 2x2 fragments with matching swizzle. Chunk index ks*4+(lane>>4) (R7 fix).
__device__ __forceinline__ void read_frags(const u16* buf, int rbase, int lane,
                                           bf16x8 (&f)[2][2]) {
#pragma unroll
  for (int i = 0; i < 2; i++)
#pragma unroll
    for (int ks = 0; ks < 2; ks++) {
      int r = rbase + i * 16 + (lane & 15);
      int slot = ((ks << 2) + (lane >> 4)) ^ (r & 7);
      f[i][ks] = *reinterpret_cast<const bf16x8*>(buf + r * 64 + slot * 8);
    }
}

__device__ __forceinline__ void mma_step(const u16* Ab, const u16* Bb, int rm, int cn,
                                         int lane, f32x4 (&acc)[2][2]) {
  bf16x8 a[2][2], b[2][2];
  read_frags(Ab, rm, lane, a);
  read_frags(Bb, cn, lane, b);
#pragma unroll
  for (int mf = 0; mf < 2; mf++)
#pragma unroll
    for (int nf = 0; nf < 2; nf++)
#pragma unroll
      for (int ks = 0; ks < 2; ks++)
        acc[mf][nf] = __builtin_amdgcn_mfma_f32_16x16x32_bf16(a[mf][ks], b[nf][ks],
                                                              acc[mf][nf], 0, 0, 0);
}

// ---------------------------------------------------------------------------
// k_prep: merged wpf (bid<1024) | trv (bid<1280) | convq (bid<2304).
__global__ __launch_bounds__(256) void k_prep(const float* __restrict__ q,
                                              const float* __restrict__ v,
                                              const float* __restrict__ kin,
                                              const float* __restrict__ alpha,
                                              u16* __restrict__ qb,
                                              u16* __restrict__ vT,
                                              u16* __restrict__ wT,
                                              u16* __restrict__ wn,
                                              float* __restrict__ pf) {
  __shared__ __align__(16) char smem[64 * 136 * 2];
  int bid = blockIdx.x;
  int tid = threadIdx.x;
  if (bid < 1024) {
    // ---- wpf: segmented scan ----
    int ng = bid & 15, b = (bid >> 4) & 3, c = bid >> 6;
    int nn = tid & 15, seg = tid >> 4;
    int n = ng * 16 + nn;
    int cb = c * BB + b;
    const int stride = BB * NN;
    size_t gbase = ((size_t)(c * CH + seg * 8) * stride) + b * NN + n;
    float lg[8], kv[8];
    float a0 = 0.f, run = 0.f;
#pragma unroll
    for (int i = 0; i < 8; i++) {
      float av = fmaxf(alpha[gbase + (size_t)i * stride], EPSF);
      kv[i] = kin[gbase + (size_t)i * stride];
      if (i == 0) a0 = av;
      run += __logf(av);
      lg[i] = run;
    }
    float (*tot)[17] = (float(*)[17])smem;
    tot[seg][nn] = run;
    __syncthreads();
    float prefix = 0.f, total = 0.f;
#pragma unroll
    for (int j = 0; j < 16; j++) {
      float tv = tot[j][nn];
      if (j < seg) prefix += tv;
      total += tv;
    }
    float rden = 1.f / (__expf(total) + EPSF);
    union { u16 u[8]; uint4 v4; } pk;
    u16* wnrow = wn + (size_t)cb * (CH * NN) + n;
#pragma unroll
    for (int i = 0; i < 8; i++) {
      float cp = __expf(prefix + lg[i]);
      u16 h = f2bf(kv[i] * (cp * rden));
      pk.u[i] = h;
      wnrow[(size_t)(seg * 8 + i) * NN] = h;
    }
    *(uint4*)(wT + (size_t)cb * (NN * CH) + (size_t)n * CH + seg * 8) = pk.v4;
    if (seg == 0) pf[cb * NN + n] = a0;
  } else if (bid < 1280) {
    // ---- trv: v -> vT transpose ----
    int b2 = bid - 1024;
    int dt = b2 & 3, cb = b2 >> 2;
    int c = cb >> 2, b = cb & 3;
    int d0 = dt * 64;
    u16* vt = (u16*)smem;  // [64][136]
    int sr = tid >> 4, chd = tid & 15;
#pragma unroll
    for (int p = 0; p < 8; p++) {
      int s = p * 16 + sr;
      float4 x = *(const float4*)&v[((size_t)(c * CH + s) * BB + b) * DD + d0 + chd * 4];
      int dbase = chd * 4;
      vt[(dbase + 0) * 136 + s] = f2bf(x.x);
      vt[(dbase + 1) * 136 + s] = f2bf(x.y);
      vt[(dbase + 2) * 136 + s] = f2bf(x.z);
      vt[(dbase + 3) * 136 + s] = f2bf(x.w);
    }
    __syncthreads();
    int dr = tid >> 2, ch = tid & 3;
    const uint4* srcl = (const uint4*)&vt[dr * 136 + ch * 32];
    uint4 a0 = srcl[0], a1 = srcl[1], a2 = srcl[2], a3 = srcl[3];
    uint4* dst = (uint4*)&vT[((size_t)cb * DD + d0 + dr) * CH + ch * 32];
    dst[0] = a0; dst[1] = a1; dst[2] = a2; dst[3] = a3;
  } else {
    // ---- convq: q fp32 -> qb bf16 ----
    size_t gid = (size_t)(bid - 1280) * 256 + tid;
    const float4* src = (const float4*)q + gid * 2;
    float4 x = src[0], z = src[1];
    union { u16 u[8]; uint4 v4; } pk;
    pk.u[0] = f2bf(x.x); pk.u[1] = f2bf(x.y); pk.u[2] = f2bf(x.z); pk.u[3] = f2bf(x.w);
    pk.u[4] = f2bf(z.x); pk.u[5] = f2bf(z.y); pk.u[6] = f2bf(z.z); pk.u[7] = f2bf(z.w);
    ((uint4*)qb)[gid] = pk.v4;
  }
}

// ---------------------------------------------------------------------------
// k_utas: bid<1024 -> UT GEMM (utT bf16 out); bid in [1024,1216) -> As GEMM.
__global__ __launch_bounds__(256) void k_utas(const u16* __restrict__ vT,
                                              const u16* __restrict__ wT,
                                              const u16* __restrict__ qb,
                                              const u16* __restrict__ wn,
                                              u16* __restrict__ utb,
                                              u16* __restrict__ asT) {
  __shared__ u16 Al[2][4096], Bl[2][4096];
  int bid = blockIdx.x;
  int tid = threadIdx.x, lane = tid & 63, wv = tid >> 6;
  int rm = (wv >> 1) * 32, cn = (wv & 1) * 32;
  if (bid < 1024) {
    int nt = bid & 3, dt = (bid >> 2) & 3, cb = bid >> 4;
    const u16* A = vT + ((size_t)cb * DD + dt * 64) * CH;
    const u16* B = wT + ((size_t)cb * NN + nt * 64) * CH;
    f32x4 acc[2][2] = {};
    stage_tile(Al[0], A, CH); stage_tile(Bl[0], B, CH);
    __syncthreads();
    stage_tile(Al[1], A + 64, CH); stage_tile(Bl[1], B + 64, CH);
    mma_step(Al[0], Bl[0], rm, cn, lane, acc);
    __syncthreads();
    mma_step(Al[1], Bl[1], rm, cn, lane, acc);
    u16* out = utb + ((size_t)cb * DD + dt * 64) * NN + nt * 64;
#pragma unroll
    for (int mf = 0; mf < 2; mf++)
#pragma unroll
      for (int nf = 0; nf < 2; nf++)
#pragma unroll
        for (int r = 0; r < 4; r++) {
          int row = rm + mf * 16 + (lane >> 4) * 4 + r;
          int col = cn + nf * 16 + (lane & 15);
          out[(size_t)row * NN + col] = f2bf(acc[mf][nf][r]);
        }
  } else {
    int bid2 = bid - 1024;
    int tile = bid2 % 3;
    int cb = bid2 / 3;
    int ti = (tile == 0) ? 0 : 1;
    int si = (tile == 2) ? 1 : 0;
    int t0 = ti * 64, s0 = si * 64;
    int c = cb >> 2, b = cb & 3;
    const u16* A = qb + ((size_t)(c * CH + t0) * BB + b) * NN;    // stride 1024
    const u16* B = wn + (size_t)cb * (CH * NN) + (size_t)s0 * NN; // stride 256
    f32x4 acc[2][2] = {};
    stage_tile(Al[0], A, BB * NN); stage_tile(Bl[0], B, NN);
    __syncthreads();
    for (int st = 0; st < 4; st++) {
      int nx = st + 1;
      if (nx < 4) {
        stage_tile(Al[nx & 1], A + nx * 64, BB * NN);
        stage_tile(Bl[nx & 1], B + nx * 64, NN);
      }
      mma_step(Al[st & 1], Bl[st & 1], rm, cn, lane, acc);
      __syncthreads();
    }
    u16* outb = asT + (size_t)cb * (CH * CH);
#pragma unroll
    for (int mf = 0; mf < 2; mf++)
#pragma unroll
      for (int nf = 0; nf < 2; nf++)
#pragma unroll
        for (int r = 0; r < 4; r++) {
          int t = t0 + rm + mf * 16 + (lane >> 4) * 4 + r;
          int s = s0 + cn + nf * 16 + (lane & 15);
          float val = (s <= t) ? acc[mf][nf][r] : 0.f;
          outb[(size_t)t * CH + s] = f2bf(val);
        }
  }
}

// ---------------------------------------------------------------------------
// k_scan: per (b,dd,n-pair): S=0; per chunk: Sp=S*pf; sptT=bf16(Sp); S=Sp+ut.
// 512 blocks x 256 threads, 2 n per thread (u32 = bf16x2).
__global__ __launch_bounds__(256) void k_scan(const u32* __restrict__ utT2,
                                              const float* __restrict__ pf,
                                              u32* __restrict__ sptT2) {
  int id = blockIdx.x * 256 + threadIdx.x;
  int nh = id & 127, dd = (id >> 7) & 255, b = id >> 15;
  float S0 = 0.f, S1 = 0.f;
  for (int ch = 0; ch < NCH; ch++) {
    int cb = ch * BB + b;
    size_t off = ((size_t)cb * DD + dd) * 128 + nh;  // u32 units (row = 128 u32)
    float2 p = *(const float2*)&pf[cb * NN + nh * 2];
    float Sp0 = S0 * p.x, Sp1 = S1 * p.y;
    sptT2[off] = (u32)f2bf(Sp0) | ((u32)f2bf(Sp1) << 16);
    u32 u = utT2[off];
    S0 = Sp0 + bf2f(u & 0xffffu);
    S1 = Sp1 + bf2f(u >> 16);
  }
}

// ---------------------------------------------------------------------------
// k_out (MFMA): y[t,d] = sum_n qb[t,n]*sptT[d,n] + sum_s AsT[t,s]*vT[d,s].
__global__ __launch_bounds__(256) void k_out(const u16* __restrict__ qb,
                                             const u16* __restrict__ sptT,
                                             const u16* __restrict__ asT,
                                             const u16* __restrict__ vT,
                                             float* __restrict__ y) {
  int bid = blockIdx.x;
  int dt = bid & 3, tt = (bid >> 2) & 1, cb = bid >> 3;
  int c = cb >> 2, b = cb & 3;
  int t0 = tt * 64, d0 = dt * 64;
  int tid = threadIdx.x, lane = tid & 63, wv = tid >> 6;
  int rm = (wv >> 1) * 32, cn = (wv & 1) * 32;
  const u16* A1 = qb + ((size_t)(c * CH + t0) * BB + b) * NN;      // stride 1024
  const u16* B1 = sptT + ((size_t)cb * DD + d0) * NN;              // stride 256
  const u16* A2 = asT + (size_t)cb * (CH * CH) + (size_t)t0 * CH;  // stride 128
  const u16* B2 = vT + ((size_t)cb * DD + d0) * CH;                // stride 128
  __shared__ u16 Al[2][4096], Bl[2][4096];
  f32x4 acc[2][2] = {};
  int nst = 5 + tt;  // tt=0: s in [0,64) only (rest masked zero, never read)
  stage_tile(Al[0], A1, BB * NN); stage_tile(Bl[0], B1, NN);
  __syncthreads();
  for (int st = 0; st < nst; st++) {
    int nx = st + 1;
    if (nx < 4) {
      stage_tile(Al[nx & 1], A1 + nx * 64, BB * NN);
      stage_tile(Bl[nx & 1], B1 + nx * 64, NN);
    } else if (nx < nst) {
      stage_tile(Al[nx & 1], A2 + (nx - 4) * 64, CH);
      stage_tile(Bl[nx & 1], B2 + (nx - 4) * 64, CH);
    }
    mma_step(Al[st & 1], Bl[st & 1], rm, cn, lane, acc);
    __syncthreads();
  }
  float* out = y + ((size_t)(c * CH + t0) * BB + b) * DD + d0;
#pragma unroll
  for (int mf = 0; mf < 2; mf++)
#pragma unroll
    for (int nf = 0; nf < 2; nf++)
#pragma unroll
      for (int r = 0; r < 4; r++) {
        int row = rm + mf * 16 + (lane >> 4) * 4 + r;
        int col = cn + nf * 16 + (lane & 15);
        out[(size_t)row * (BB * DD) + col] = acc[mf][nf][r];
      }
}

// ---------------------------------------------------------------------------
extern "C" void kernel_launch(void* const* d_in, const int* in_sizes, int n_in,
                              void* d_out, int out_size, void* d_ws, size_t ws_size,
                              hipStream_t stream) {
  const float* v = (const float*)d_in[0];
  const float* k = (const float*)d_in[1];
  const float* alpha = (const float*)d_in[2];
  const float* q = (const float*)d_in[3];
  float* y = (float*)d_out;
  char* ws = (char*)d_ws;
  u16* qb = (u16*)(ws + WS_QB);
  u16* vT = (u16*)(ws + WS_VT);
  u16* wT = (u16*)(ws + WS_WT);
  u16* wn = (u16*)(ws + WS_WN);
  u16* asT = (u16*)(ws + WS_AST);
  u16* sptT = (u16*)(ws + WS_SPT);
  float* pf = (float*)(ws + WS_PF);
  u16* utb = (u16*)(ws + WS_UT);

  k_prep<<<2304, 256, 0, stream>>>(q, v, k, alpha, qb, vT, wT, wn, pf);
  k_utas<<<1216, 256, 0, stream>>>(vT, wT, qb, wn, utb, asT);
  k_scan<<<512, 256, 0, stream>>>((const u32*)utb, pf, (u32*)sptT);
  k_out<<<512, 256, 0, stream>>>(qb, sptT, asT, vT, y);
}

// Round 11
// 40.469 us; speedup vs baseline: 1.4204x; 1.0130x over previous
//
#include <hip/hip_runtime.h>
#include <math.h>

typedef unsigned short u16;
typedef unsigned int u32;
typedef __bf16 bf16x8 __attribute__((ext_vector_type(8)));
typedef float f32x4 __attribute__((ext_vector_type(4)));

// Problem constants
#define BB   4      // B
#define DD   256    // d
#define NN   256    // n
#define CH   128    // CHUNK
#define NCH  16     // T/CHUNK
#define EPSF 1e-8f

// Workspace byte offsets
#define WS_QB  0u           // qb   bf16 [T][B][N]          4 MB
#define WS_VT  (4u<<20)     // vT   bf16 [CB][D][S=128]     4 MB
#define WS_WT  (8u<<20)     // wT   bf16 [CB][N][S=128]     4 MB
#define WS_WN  (12u<<20)    // w_n  bf16 [CB][S][N]         4 MB
#define WS_AST (16u<<20)    // AsT  bf16 [CB][T=128][S=128] 2 MB
#define WS_SPT (18u<<20)    // sptT bf16 [CB][D][N]         8 MB
#define WS_PF  (26u<<20)    // pf   f32  [CB][N]            64 KB
#define WS_UT  (28u<<20)    // utT  bf16 [CB][D][N]         8 MB

__device__ __forceinline__ u16 f2bf(float x) {
  u32 u = __float_as_uint(x);
  u32 r = (u + 0x7fffu + ((u >> 16) & 1u)) >> 16;
  return (u16)r;
}
__device__ __forceinline__ float bf2f(u32 lo16) {
  return __uint_as_float(lo16 << 16);
}

__device__ __forceinline__ void gload16(void* lds, const void* g) {
  __builtin_amdgcn_global_load_lds((const __attribute__((address_space(1))) void*)g,
                                   (__attribute__((address_space(3))) void*)lds, 16, 0, 0);
}

// Stage a 64x64 bf16 tile (row-major, rowstride in elems) into linear LDS.
// Slot-XOR swizzle applied on the GLOBAL source address (m173 pattern).
__device__ __forceinline__ void stage_tile(u16* lds, const u16* g, int rowstride) {
  int tid = threadIdx.x;
#pragma unroll
  for (int h = 0; h < 2; h++) {
    int ci = tid + h * 256;
    int r = ci >> 3, sl = ci & 7;
    const u16* src = g + (size_t)r * rowstride + ((sl ^ (r & 7)) << 3);
    gload16(lds + (size_t)ci * 8, src);
  }
}

// Read 2x2 fragments with matching swizzle. Chunk index ks*4+(lane>>4) (R7 fix).
__device__ __forceinline__ void read_frags(const u16* buf, int rbase, int lane,
                                           bf16x8 (&f)[2][2]) {
#pragma unroll
  for (int i = 0; i < 2; i++)
#pragma unroll
    for (int ks = 0; ks < 2; ks++) {
      int r = rbase + i * 16 + (lane & 15);
      int slot = ((ks << 2) + (lane >> 4)) ^ (r & 7);
      f[i][ks] = *reinterpret_cast<const bf16x8*>(buf + r * 64 + slot * 8);
    }
}

__device__ __forceinline__ void mma_step(const u16* Ab, const u16* Bb, int rm, int cn,
                                         int lane, f32x4 (&acc)[2][2]) {
  bf16x8 a[2][2], b[2][2];
  read_frags(Ab, rm, lane, a);
  read_frags(Bb, cn, lane, b);
#pragma unroll
  for (int mf = 0; mf < 2; mf++)
#pragma unroll
    for (int nf = 0; nf < 2; nf++)
#pragma unroll
      for (int ks = 0; ks < 2; ks++)
        acc[mf][nf] = __builtin_amdgcn_mfma_f32_16x16x32_bf16(a[mf][ks], b[nf][ks],
                                                              acc[mf][nf], 0, 0, 0);
}

// ---------------------------------------------------------------------------
// k_prep: merged wpf (bid<1024) | trv (bid<1280) | convq (bid<2304).
__global__ __launch_bounds__(256) void k_prep(const float* __restrict__ q,
                                              const float* __restrict__ v,
                                              const float* __restrict__ kin,
                                              const float* __restrict__ alpha,
                                              u16* __restrict__ qb,
                                              u16* __restrict__ vT,
                                              u16* __restrict__ wT,
                                              u16* __restrict__ wn,
                                              float* __restrict__ pf) {
  __shared__ __align__(16) char smem[64 * 136 * 2];
  int bid = blockIdx.x;
  int tid = threadIdx.x;
  if (bid < 1024) {
    // ---- wpf: segmented scan ----
    int ng = bid & 15, b = (bid >> 4) & 3, c = bid >> 6;
    int nn = tid & 15, seg = tid >> 4;
    int n = ng * 16 + nn;
    int cb = c * BB + b;
    const int stride = BB * NN;
    size_t gbase = ((size_t)(c * CH + seg * 8) * stride) + b * NN + n;
    float lg[8], kv[8];
    float a0 = 0.f, run = 0.f;
#pragma unroll
    for (int i = 0; i < 8; i++) {
      float av = fmaxf(alpha[gbase + (size_t)i * stride], EPSF);
      kv[i] = kin[gbase + (size_t)i * stride];
      if (i == 0) a0 = av;
      run += __logf(av);
      lg[i] = run;
    }
    float (*tot)[17] = (float(*)[17])smem;
    tot[seg][nn] = run;
    __syncthreads();
    float prefix = 0.f, total = 0.f;
#pragma unroll
    for (int j = 0; j < 16; j++) {
      float tv = tot[j][nn];
      if (j < seg) prefix += tv;
      total += tv;
    }
    float rden = 1.f / (__expf(total) + EPSF);
    union { u16 u[8]; uint4 v4; } pk;
    u16* wnrow = wn + (size_t)cb * (CH * NN) + n;
#pragma unroll
    for (int i = 0; i < 8; i++) {
      float cp = __expf(prefix + lg[i]);
      u16 h = f2bf(kv[i] * (cp * rden));
      pk.u[i] = h;
      wnrow[(size_t)(seg * 8 + i) * NN] = h;
    }
    *(uint4*)(wT + (size_t)cb * (NN * CH) + (size_t)n * CH + seg * 8) = pk.v4;
    if (seg == 0) pf[cb * NN + n] = a0;
  } else if (bid < 1280) {
    // ---- trv: v -> vT transpose ----
    int b2 = bid - 1024;
    int dt = b2 & 3, cb = b2 >> 2;
    int c = cb >> 2, b = cb & 3;
    int d0 = dt * 64;
    u16* vt = (u16*)smem;  // [64][136]
    int sr = tid >> 4, chd = tid & 15;
#pragma unroll
    for (int p = 0; p < 8; p++) {
      int s = p * 16 + sr;
      float4 x = *(const float4*)&v[((size_t)(c * CH + s) * BB + b) * DD + d0 + chd * 4];
      int dbase = chd * 4;
      vt[(dbase + 0) * 136 + s] = f2bf(x.x);
      vt[(dbase + 1) * 136 + s] = f2bf(x.y);
      vt[(dbase + 2) * 136 + s] = f2bf(x.z);
      vt[(dbase + 3) * 136 + s] = f2bf(x.w);
    }
    __syncthreads();
    int dr = tid >> 2, ch = tid & 3;
    const uint4* srcl = (const uint4*)&vt[dr * 136 + ch * 32];
    uint4 a0 = srcl[0], a1 = srcl[1], a2 = srcl[2], a3 = srcl[3];
    uint4* dst = (uint4*)&vT[((size_t)cb * DD + d0 + dr) * CH + ch * 32];
    dst[0] = a0; dst[1] = a1; dst[2] = a2; dst[3] = a3;
  } else {
    // ---- convq: q fp32 -> qb bf16 ----
    size_t gid = (size_t)(bid - 1280) * 256 + tid;
    const float4* src = (const float4*)q + gid * 2;
    float4 x = src[0], z = src[1];
    union { u16 u[8]; uint4 v4; } pk;
    pk.u[0] = f2bf(x.x); pk.u[1] = f2bf(x.y); pk.u[2] = f2bf(x.z); pk.u[3] = f2bf(x.w);
    pk.u[4] = f2bf(z.x); pk.u[5] = f2bf(z.y); pk.u[6] = f2bf(z.z); pk.u[7] = f2bf(z.w);
    ((uint4*)qb)[gid] = pk.v4;
  }
}

// ---------------------------------------------------------------------------
// k_utas: bid<1024 -> UT GEMM (single-stage K=128, utT bf16 out);
//         bid in [1024,1216) -> As GEMM (dbuf K=256).
__global__ __launch_bounds__(256) void k_utas(const u16* __restrict__ vT,
                                              const u16* __restrict__ wT,
                                              const u16* __restrict__ qb,
                                              const u16* __restrict__ wn,
                                              u16* __restrict__ utb,
                                              u16* __restrict__ asT) {
  __shared__ u16 Al[2][4096], Bl[2][4096];
  int bid = blockIdx.x;
  int tid = threadIdx.x, lane = tid & 63, wv = tid >> 6;
  int rm = (wv >> 1) * 32, cn = (wv & 1) * 32;
  if (bid < 1024) {
    int nt = bid & 3, dt = (bid >> 2) & 3, cb = bid >> 4;
    const u16* A = vT + ((size_t)cb * DD + dt * 64) * CH;
    const u16* B = wT + ((size_t)cb * NN + nt * 64) * CH;
    f32x4 acc[2][2] = {};
    // single stage: all four 64x64 subtiles in flight at once, one barrier
    stage_tile(Al[0], A, CH); stage_tile(Al[1], A + 64, CH);
    stage_tile(Bl[0], B, CH); stage_tile(Bl[1], B + 64, CH);
    __syncthreads();
    mma_step(Al[0], Bl[0], rm, cn, lane, acc);
    mma_step(Al[1], Bl[1], rm, cn, lane, acc);
    u16* out = utb + ((size_t)cb * DD + dt * 64) * NN + nt * 64;
#pragma unroll
    for (int mf = 0; mf < 2; mf++)
#pragma unroll
      for (int nf = 0; nf < 2; nf++)
#pragma unroll
        for (int r = 0; r < 4; r++) {
          int row = rm + mf * 16 + (lane >> 4) * 4 + r;
          int col = cn + nf * 16 + (lane & 15);
          out[(size_t)row * NN + col] = f2bf(acc[mf][nf][r]);
        }
  } else {
    int bid2 = bid - 1024;
    int tile = bid2 % 3;
    int cb = bid2 / 3;
    int ti = (tile == 0) ? 0 : 1;
    int si = (tile == 2) ? 1 : 0;
    int t0 = ti * 64, s0 = si * 64;
    int c = cb >> 2, b = cb & 3;
    const u16* A = qb + ((size_t)(c * CH + t0) * BB + b) * NN;    // stride 1024
    const u16* B = wn + (size_t)cb * (CH * NN) + (size_t)s0 * NN; // stride 256
    f32x4 acc[2][2] = {};
    stage_tile(Al[0], A, BB * NN); stage_tile(Bl[0], B, NN);
    __syncthreads();
    for (int st = 0; st < 4; st++) {
      int nx = st + 1;
      if (nx < 4) {
        stage_tile(Al[nx & 1], A + nx * 64, BB * NN);
        stage_tile(Bl[nx & 1], B + nx * 64, NN);
      }
      mma_step(Al[st & 1], Bl[st & 1], rm, cn, lane, acc);
      __syncthreads();
    }
    u16* outb = asT + (size_t)cb * (CH * CH);
#pragma unroll
    for (int mf = 0; mf < 2; mf++)
#pragma unroll
      for (int nf = 0; nf < 2; nf++)
#pragma unroll
        for (int r = 0; r < 4; r++) {
          int t = t0 + rm + mf * 16 + (lane >> 4) * 4 + r;
          int s = s0 + cn + nf * 16 + (lane & 15);
          float val = (s <= t) ? acc[mf][nf][r] : 0.f;
          outb[(size_t)t * CH + s] = f2bf(val);
        }
  }
}

// ---------------------------------------------------------------------------
// k_scan: batched-load version. All 16 chunk load addresses are data-
// independent -> issue every utb/pf load up front (1x latency), then the
// serial S-update consumes from registers. 512 blocks x 256, 2 n per thread.
__global__ __launch_bounds__(256) void k_scan(const u32* __restrict__ utT2,
                                              const float* __restrict__ pf,
                                              u32* __restrict__ sptT2) {
  int id = blockIdx.x * 256 + threadIdx.x;
  int nh = id & 127, dd = (id >> 7) & 255, b = id >> 15;
  u32 u[NCH];
  float2 pp[NCH];
#pragma unroll
  for (int ch = 0; ch < NCH; ch++) {
    int cb = ch * BB + b;
    u[ch] = utT2[((size_t)cb * DD + dd) * 128 + nh];
    pp[ch] = *(const float2*)&pf[cb * NN + nh * 2];
  }
  float S0 = 0.f, S1 = 0.f;
#pragma unroll
  for (int ch = 0; ch < NCH; ch++) {
    int cb = ch * BB + b;
    float Sp0 = S0 * pp[ch].x, Sp1 = S1 * pp[ch].y;
    sptT2[((size_t)cb * DD + dd) * 128 + nh] = (u32)f2bf(Sp0) | ((u32)f2bf(Sp1) << 16);
    S0 = Sp0 + bf2f(u[ch] & 0xffffu);
    S1 = Sp1 + bf2f(u[ch] >> 16);
  }
}

// ---------------------------------------------------------------------------
// k_out (MFMA): y[t,d] = sum_n qb[t,n]*sptT[d,n] + sum_s AsT[t,s]*vT[d,s].
__global__ __launch_bounds__(256) void k_out(const u16* __restrict__ qb,
                                             const u16* __restrict__ sptT,
                                             const u16* __restrict__ asT,
                                             const u16* __restrict__ vT,
                                             float* __restrict__ y) {
  int bid = blockIdx.x;
  int dt = bid & 3, tt = (bid >> 2) & 1, cb = bid >> 3;
  int c = cb >> 2, b = cb & 3;
  int t0 = tt * 64, d0 = dt * 64;
  int tid = threadIdx.x, lane = tid & 63, wv = tid >> 6;
  int rm = (wv >> 1) * 32, cn = (wv & 1) * 32;
  const u16* A1 = qb + ((size_t)(c * CH + t0) * BB + b) * NN;      // stride 1024
  const u16* B1 = sptT + ((size_t)cb * DD + d0) * NN;              // stride 256
  const u16* A2 = asT + (size_t)cb * (CH * CH) + (size_t)t0 * CH;  // stride 128
  const u16* B2 = vT + ((size_t)cb * DD + d0) * CH;                // stride 128
  __shared__ u16 Al[2][4096], Bl[2][4096];
  f32x4 acc[2][2] = {};
  int nst = 5 + tt;  // tt=0: s in [0,64) only (rest masked zero, never read)
  stage_tile(Al[0], A1, BB * NN); stage_tile(Bl[0], B1, NN);
  __syncthreads();
  for (int st = 0; st < nst; st++) {
    int nx = st + 1;
    if (nx < 4) {
      stage_tile(Al[nx & 1], A1 + nx * 64, BB * NN);
      stage_tile(Bl[nx & 1], B1 + nx * 64, NN);
    } else if (nx < nst) {
      stage_tile(Al[nx & 1], A2 + (nx - 4) * 64, CH);
      stage_tile(Bl[nx & 1], B2 + (nx - 4) * 64, CH);
    }
    mma_step(Al[st & 1], Bl[st & 1], rm, cn, lane, acc);
    __syncthreads();
  }
  float* out = y + ((size_t)(c * CH + t0) * BB + b) * DD + d0;
#pragma unroll
  for (int mf = 0; mf < 2; mf++)
#pragma unroll
    for (int nf = 0; nf < 2; nf++)
#pragma unroll
      for (int r = 0; r < 4; r++) {
        int row = rm + mf * 16 + (lane >> 4) * 4 + r;
        int col = cn + nf * 16 + (lane & 15);
        out[(size_t)row * (BB * DD) + col] = acc[mf][nf][r];
      }
}

// ---------------------------------------------------------------------------
extern "C" void kernel_launch(void* const* d_in, const int* in_sizes, int n_in,
                              void* d_out, int out_size, void* d_ws, size_t ws_size,
                              hipStream_t stream) {
  const float* v = (const float*)d_in[0];
  const float* k = (const float*)d_in[1];
  const float* alpha = (const float*)d_in[2];
  const float* q = (const float*)d_in[3];
  float* y = (float*)d_out;
  char* ws = (char*)d_ws;
  u16* qb = (u16*)(ws + WS_QB);
  u16* vT = (u16*)(ws + WS_VT);
  u16* wT = (u16*)(ws + WS_WT);
  u16* wn = (u16*)(ws + WS_WN);
  u16* asT = (u16*)(ws + WS_AST);
  u16* sptT = (u16*)(ws + WS_SPT);
  float* pf = (float*)(ws + WS_PF);
  u16* utb = (u16*)(ws + WS_UT);

  k_prep<<<2304, 256, 0, stream>>>(q, v, k, alpha, qb, vT, wT, wn, pf);
  k_utas<<<1216, 256, 0, stream>>>(vT, wT, qb, wn, utb, asT);
  k_scan<<<512, 256, 0, stream>>>((const u32*)utb, pf, (u32*)sptT);
  k_out<<<512, 256, 0, stream>>>(qb, sptT, asT, vT, y);
}

// Round 12
// 35.787 us; speedup vs baseline: 1.6063x; 1.1308x over previous
//
#include <hip/hip_runtime.h>
#include <math.h>

typedef unsigned short u16;
typedef unsigned int u32;
typedef __bf16 bf16x8 __attribute__((ext_vector_type(8)));
typedef float f32x4 __attribute__((ext_vector_type(4)));

// Problem constants
#define BB   4      // B
#define DD   256    // d
#define NN   256    // n
#define CH   128    // CHUNK
#define NCH  16     // T/CHUNK
#define EPSF 1e-8f

// Workspace byte offsets
#define WS_QB  0u           // qb   bf16 [T][B][N]          4 MB
#define WS_VT  (4u<<20)     // vT   bf16 [CB][D][S=128]     4 MB
#define WS_WT  (8u<<20)     // wT   bf16 [CB][N][S=128]     4 MB
#define WS_WN  (12u<<20)    // w_n  bf16 [CB][S][N]         4 MB
#define WS_AST (16u<<20)    // AsT  bf16 [CB][T=128][S=128] 2 MB
#define WS_SPT (18u<<20)    // sptT bf16 [CB][D][N]         8 MB
#define WS_PF  (26u<<20)    // pf   f32  [CB][N]            64 KB
#define WS_UT  (28u<<20)    // utT  bf16 [CB][D][N]         8 MB

__device__ __forceinline__ u16 f2bf(float x) {
  u32 u = __float_as_uint(x);
  u32 r = (u + 0x7fffu + ((u >> 16) & 1u)) >> 16;
  return (u16)r;
}
__device__ __forceinline__ float bf2f(u32 lo16) {
  return __uint_as_float(lo16 << 16);
}

// Bijective XCD swizzle (grid % 8 == 0): contiguous logical ids per XCD.
__device__ __forceinline__ int xcd_swz(int bid, int nwg) {
  return (bid & 7) * (nwg >> 3) + (bid >> 3);
}

__device__ __forceinline__ void gload16(void* lds, const void* g) {
  __builtin_amdgcn_global_load_lds((const __attribute__((address_space(1))) void*)g,
                                   (__attribute__((address_space(3))) void*)lds, 16, 0, 0);
}

// Stage a 64x64 bf16 tile (row-major, rowstride in elems) into linear LDS.
// Slot-XOR swizzle applied on the GLOBAL source address (m173 pattern).
__device__ __forceinline__ void stage_tile(u16* lds, const u16* g, int rowstride) {
  int tid = threadIdx.x;
#pragma unroll
  for (int h = 0; h < 2; h++) {
    int ci = tid + h * 256;
    int r = ci >> 3, sl = ci & 7;
    const u16* src = g + (size_t)r * rowstride + ((sl ^ (r & 7)) << 3);
    gload16(lds + (size_t)ci * 8, src);
  }
}

// Read 2x2 fragments with matching swizzle. Chunk index ks*4+(lane>>4) (R7 fix).
__device__ __forceinline__ void read_frags(const u16* buf, int rbase, int lane,
                                           bf16x8 (&f)[2][2]) {
#pragma unroll
  for (int i = 0; i < 2; i++)
#pragma unroll
    for (int ks = 0; ks < 2; ks++) {
      int r = rbase + i * 16 + (lane & 15);
      int slot = ((ks << 2) + (lane >> 4)) ^ (r & 7);
      f[i][ks] = *reinterpret_cast<const bf16x8*>(buf + r * 64 + slot * 8);
    }
}

__device__ __forceinline__ void mma_step(const u16* Ab, const u16* Bb, int rm, int cn,
                                         int lane, f32x4 (&acc)[2][2]) {
  bf16x8 a[2][2], b[2][2];
  read_frags(Ab, rm, lane, a);
  read_frags(Bb, cn, lane, b);
#pragma unroll
  for (int mf = 0; mf < 2; mf++)
#pragma unroll
    for (int nf = 0; nf < 2; nf++)
#pragma unroll
      for (int ks = 0; ks < 2; ks++)
        acc[mf][nf] = __builtin_amdgcn_mfma_f32_16x16x32_bf16(a[mf][ks], b[nf][ks],
                                                              acc[mf][nf], 0, 0, 0);
}

// ---------------------------------------------------------------------------
// k_prep: merged wpf (bid<1024) | trv (bid<1280) | convq (bid<2304).
__global__ __launch_bounds__(256) void k_prep(const float* __restrict__ q,
                                              const float* __restrict__ v,
                                              const float* __restrict__ kin,
                                              const float* __restrict__ alpha,
                                              u16* __restrict__ qb,
                                              u16* __restrict__ vT,
                                              u16* __restrict__ wT,
                                              u16* __restrict__ wn,
                                              float* __restrict__ pf) {
  __shared__ __align__(16) char smem[64 * 136 * 2];
  int bid = blockIdx.x;
  int tid = threadIdx.x;
  if (bid < 1024) {
    // ---- wpf: segmented scan ----
    int ng = bid & 15, b = (bid >> 4) & 3, c = bid >> 6;
    int nn = tid & 15, seg = tid >> 4;
    int n = ng * 16 + nn;
    int cb = c * BB + b;
    const int stride = BB * NN;
    size_t gbase = ((size_t)(c * CH + seg * 8) * stride) + b * NN + n;
    float lg[8], kv[8];
    float a0 = 0.f, run = 0.f;
#pragma unroll
    for (int i = 0; i < 8; i++) {
      float av = fmaxf(alpha[gbase + (size_t)i * stride], EPSF);
      kv[i] = kin[gbase + (size_t)i * stride];
      if (i == 0) a0 = av;
      run += __logf(av);
      lg[i] = run;
    }
    float (*tot)[17] = (float(*)[17])smem;
    tot[seg][nn] = run;
    __syncthreads();
    float prefix = 0.f, total = 0.f;
#pragma unroll
    for (int j = 0; j < 16; j++) {
      float tv = tot[j][nn];
      if (j < seg) prefix += tv;
      total += tv;
    }
    float rden = 1.f / (__expf(total) + EPSF);
    union { u16 u[8]; uint4 v4; } pk;
    u16* wnrow = wn + (size_t)cb * (CH * NN) + n;
#pragma unroll
    for (int i = 0; i < 8; i++) {
      float cp = __expf(prefix + lg[i]);
      u16 h = f2bf(kv[i] * (cp * rden));
      pk.u[i] = h;
      wnrow[(size_t)(seg * 8 + i) * NN] = h;
    }
    *(uint4*)(wT + (size_t)cb * (NN * CH) + (size_t)n * CH + seg * 8) = pk.v4;
    if (seg == 0) pf[cb * NN + n] = a0;
  } else if (bid < 1280) {
    // ---- trv: v -> vT transpose ----
    int b2 = bid - 1024;
    int dt = b2 & 3, cb = b2 >> 2;
    int c = cb >> 2, b = cb & 3;
    int d0 = dt * 64;
    u16* vt = (u16*)smem;  // [64][136]
    int sr = tid >> 4, chd = tid & 15;
#pragma unroll
    for (int p = 0; p < 8; p++) {
      int s = p * 16 + sr;
      float4 x = *(const float4*)&v[((size_t)(c * CH + s) * BB + b) * DD + d0 + chd * 4];
      int dbase = chd * 4;
      vt[(dbase + 0) * 136 + s] = f2bf(x.x);
      vt[(dbase + 1) * 136 + s] = f2bf(x.y);
      vt[(dbase + 2) * 136 + s] = f2bf(x.z);
      vt[(dbase + 3) * 136 + s] = f2bf(x.w);
    }
    __syncthreads();
    int dr = tid >> 2, ch = tid & 3;
    const uint4* srcl = (const uint4*)&vt[dr * 136 + ch * 32];
    uint4 a0 = srcl[0], a1 = srcl[1], a2 = srcl[2], a3 = srcl[3];
    uint4* dst = (uint4*)&vT[((size_t)cb * DD + d0 + dr) * CH + ch * 32];
    dst[0] = a0; dst[1] = a1; dst[2] = a2; dst[3] = a3;
  } else {
    // ---- convq: q fp32 -> qb bf16 ----
    size_t gid = (size_t)(bid - 1280) * 256 + tid;
    const float4* src = (const float4*)q + gid * 2;
    float4 x = src[0], z = src[1];
    union { u16 u[8]; uint4 v4; } pk;
    pk.u[0] = f2bf(x.x); pk.u[1] = f2bf(x.y); pk.u[2] = f2bf(x.z); pk.u[3] = f2bf(x.w);
    pk.u[4] = f2bf(z.x); pk.u[5] = f2bf(z.y); pk.u[6] = f2bf(z.z); pk.u[7] = f2bf(z.w);
    ((uint4*)qb)[gid] = pk.v4;
  }
}

// ---------------------------------------------------------------------------
// k_ut: UT GEMM only (uniform, 1024 blocks, XCD-swizzled; single-stage K=128).
__global__ __launch_bounds__(256) void k_ut(const u16* __restrict__ vT,
                                            const u16* __restrict__ wT,
                                            u16* __restrict__ utb) {
  __shared__ u16 Al[2][4096], Bl[2][4096];
  int bid = xcd_swz(blockIdx.x, 1024);
  int tid = threadIdx.x, lane = tid & 63, wv = tid >> 6;
  int rm = (wv >> 1) * 32, cn = (wv & 1) * 32;
  int nt = bid & 3, dt = (bid >> 2) & 3, cb = bid >> 4;
  const u16* A = vT + ((size_t)cb * DD + dt * 64) * CH;
  const u16* B = wT + ((size_t)cb * NN + nt * 64) * CH;
  f32x4 acc[2][2] = {};
  stage_tile(Al[0], A, CH); stage_tile(Al[1], A + 64, CH);
  stage_tile(Bl[0], B, CH); stage_tile(Bl[1], B + 64, CH);
  __syncthreads();
  mma_step(Al[0], Bl[0], rm, cn, lane, acc);
  mma_step(Al[1], Bl[1], rm, cn, lane, acc);
  u16* out = utb + ((size_t)cb * DD + dt * 64) * NN + nt * 64;
#pragma unroll
  for (int mf = 0; mf < 2; mf++)
#pragma unroll
    for (int nf = 0; nf < 2; nf++)
#pragma unroll
      for (int r = 0; r < 4; r++) {
        int row = rm + mf * 16 + (lane >> 4) * 4 + r;
        int col = cn + nf * 16 + (lane & 15);
        out[(size_t)row * NN + col] = f2bf(acc[mf][nf][r]);
      }
}

// ---------------------------------------------------------------------------
// k_scanas: bid<192 -> As GEMM (long blocks first); bid in [192,704) -> scan.
__global__ __launch_bounds__(256) void k_scanas(const u16* __restrict__ qb,
                                                const u16* __restrict__ wn,
                                                const u32* __restrict__ utT2,
                                                const float* __restrict__ pf,
                                                u16* __restrict__ asT,
                                                u32* __restrict__ sptT2) {
  __shared__ u16 Al[2][4096], Bl[2][4096];
  int bid = blockIdx.x;
  int tid = threadIdx.x;
  if (bid < 192) {
    int lane = tid & 63, wv = tid >> 6;
    int rm = (wv >> 1) * 32, cn = (wv & 1) * 32;
    int tile = bid % 3;
    int cb = bid / 3;
    int ti = (tile == 0) ? 0 : 1;
    int si = (tile == 2) ? 1 : 0;
    int t0 = ti * 64, s0 = si * 64;
    int c = cb >> 2, b = cb & 3;
    const u16* A = qb + ((size_t)(c * CH + t0) * BB + b) * NN;    // stride 1024
    const u16* B = wn + (size_t)cb * (CH * NN) + (size_t)s0 * NN; // stride 256
    f32x4 acc[2][2] = {};
    stage_tile(Al[0], A, BB * NN); stage_tile(Bl[0], B, NN);
    __syncthreads();
    for (int st = 0; st < 4; st++) {
      int nx = st + 1;
      if (nx < 4) {
        stage_tile(Al[nx & 1], A + nx * 64, BB * NN);
        stage_tile(Bl[nx & 1], B + nx * 64, NN);
      }
      mma_step(Al[st & 1], Bl[st & 1], rm, cn, lane, acc);
      __syncthreads();
    }
    u16* outb = asT + (size_t)cb * (CH * CH);
#pragma unroll
    for (int mf = 0; mf < 2; mf++)
#pragma unroll
      for (int nf = 0; nf < 2; nf++)
#pragma unroll
        for (int r = 0; r < 4; r++) {
          int t = t0 + rm + mf * 16 + (lane >> 4) * 4 + r;
          int s = s0 + cn + nf * 16 + (lane & 15);
          float val = (s <= t) ? acc[mf][nf][r] : 0.f;
          outb[(size_t)t * CH + s] = f2bf(val);
        }
  } else {
    // ---- scan: batched loads, serial S-update. 512 works, 1 u32/thread.
    int id = (bid - 192) * 256 + tid;
    int nh = id & 127, dd = (id >> 7) & 255, b = id >> 15;
    u32 u[NCH];
    float2 pp[NCH];
#pragma unroll
    for (int ch = 0; ch < NCH; ch++) {
      int cb = ch * BB + b;
      u[ch] = utT2[((size_t)cb * DD + dd) * 128 + nh];
      pp[ch] = *(const float2*)&pf[cb * NN + nh * 2];
    }
    float S0 = 0.f, S1 = 0.f;
#pragma unroll
    for (int ch = 0; ch < NCH; ch++) {
      int cb = ch * BB + b;
      float Sp0 = S0 * pp[ch].x, Sp1 = S1 * pp[ch].y;
      sptT2[((size_t)cb * DD + dd) * 128 + nh] = (u32)f2bf(Sp0) | ((u32)f2bf(Sp1) << 16);
      S0 = Sp0 + bf2f(u[ch] & 0xffffu);
      S1 = Sp1 + bf2f(u[ch] >> 16);
    }
  }
}

// ---------------------------------------------------------------------------
// k_out (MFMA): y[t,d] = sum_n qb[t,n]*sptT[d,n] + sum_s AsT[t,s]*vT[d,s].
// XCD-swizzled (512 blocks).
__global__ __launch_bounds__(256) void k_out(const u16* __restrict__ qb,
                                             const u16* __restrict__ sptT,
                                             const u16* __restrict__ asT,
                                             const u16* __restrict__ vT,
                                             float* __restrict__ y) {
  int bid = xcd_swz(blockIdx.x, 512);
  int dt = bid & 3, tt = (bid >> 2) & 1, cb = bid >> 3;
  int c = cb >> 2, b = cb & 3;
  int t0 = tt * 64, d0 = dt * 64;
  int tid = threadIdx.x, lane = tid & 63, wv = tid >> 6;
  int rm = (wv >> 1) * 32, cn = (wv & 1) * 32;
  const u16* A1 = qb + ((size_t)(c * CH + t0) * BB + b) * NN;      // stride 1024
  const u16* B1 = sptT + ((size_t)cb * DD + d0) * NN;              // stride 256
  const u16* A2 = asT + (size_t)cb * (CH * CH) + (size_t)t0 * CH;  // stride 128
  const u16* B2 = vT + ((size_t)cb * DD + d0) * CH;                // stride 128
  __shared__ u16 Al[2][4096], Bl[2][4096];
  f32x4 acc[2][2] = {};
  int nst = 5 + tt;  // tt=0: s in [0,64) only (rest masked zero, never read)
  stage_tile(Al[0], A1, BB * NN); stage_tile(Bl[0], B1, NN);
  __syncthreads();
  for (int st = 0; st < nst; st++) {
    int nx = st + 1;
    if (nx < 4) {
      stage_tile(Al[nx & 1], A1 + nx * 64, BB * NN);
      stage_tile(Bl[nx & 1], B1 + nx * 64, NN);
    } else if (nx < nst) {
      stage_tile(Al[nx & 1], A2 + (nx - 4) * 64, CH);
      stage_tile(Bl[nx & 1], B2 + (nx - 4) * 64, CH);
    }
    mma_step(Al[st & 1], Bl[st & 1], rm, cn, lane, acc);
    __syncthreads();
  }
  float* out = y + ((size_t)(c * CH + t0) * BB + b) * DD + d0;
#pragma unroll
  for (int mf = 0; mf < 2; mf++)
#pragma unroll
    for (int nf = 0; nf < 2; nf++)
#pragma unroll
      for (int r = 0; r < 4; r++) {
        int row = rm + mf * 16 + (lane >> 4) * 4 + r;
        int col = cn + nf * 16 + (lane & 15);
        out[(size_t)row * (BB * DD) + col] = acc[mf][nf][r];
      }
}

// ---------------------------------------------------------------------------
extern "C" void kernel_launch(void* const* d_in, const int* in_sizes, int n_in,
                              void* d_out, int out_size, void* d_ws, size_t ws_size,
                              hipStream_t stream) {
  const float* v = (const float*)d_in[0];
  const float* k = (const float*)d_in[1];
  const float* alpha = (const float*)d_in[2];
  const float* q = (const float*)d_in[3];
  float* y = (float*)d_out;
  char* ws = (char*)d_ws;
  u16* qb = (u16*)(ws + WS_QB);
  u16* vT = (u16*)(ws + WS_VT);
  u16* wT = (u16*)(ws + WS_WT);
  u16* wn = (u16*)(ws + WS_WN);
  u16* asT = (u16*)(ws + WS_AST);
  u16* sptT = (u16*)(ws + WS_SPT);
  float* pf = (float*)(ws + WS_PF);
  u16* utb = (u16*)(ws + WS_UT);

  k_prep<<<2304, 256, 0, stream>>>(q, v, k, alpha, qb, vT, wT, wn, pf);
  k_ut<<<1024, 256, 0, stream>>>(vT, wT, utb);
  k_scanas<<<704, 256, 0, stream>>>(qb, wn, (const u32*)utb, pf, asT, (u32*)sptT);
  k_out<<<512, 256, 0, stream>>>(qb, sptT, asT, vT, y);
}